// Round 2
// baseline (1746.118 us; speedup 1.0000x reference)
//
#include <hip/hip_runtime.h>

#define NN 50000
#define EE 800000
// D = 64, one wave (64 lanes) handles one node-row / edge-row

// ---------- float atomic-max via order-preserving uint mapping ----------
__device__ __forceinline__ unsigned fmap(float f) {
    unsigned b = __float_as_uint(f);
    return (b & 0x80000000u) ? ~b : (b | 0x80000000u);
}
__device__ __forceinline__ float funmap(unsigned u) {
    return (u & 0x80000000u) ? __uint_as_float(u & 0x7fffffffu)
                             : __uint_as_float(~u);
}

// ---------- K0: Wqe = Wq @ We^T  [64x64], bqe = bq @ We^T [64] ----------
__global__ __launch_bounds__(64) void fuse_weights(
    const float* __restrict__ Wq, const float* __restrict__ We,
    const float* __restrict__ bq, float* __restrict__ Wqe,
    float* __restrict__ bqe) {
    int j = threadIdx.x;      // output col (0..63)
    int t = blockIdx.x;       // row (0..63), 64 == bias row
    if (t < 64) {
        float acc = 0.f;
        #pragma unroll
        for (int d = 0; d < 64; ++d) acc = fmaf(Wq[t * 64 + d], We[j * 64 + d], acc);
        Wqe[t * 64 + j] = acc;
    } else {
        float acc = 0.f;
        #pragma unroll
        for (int d = 0; d < 64; ++d) acc = fmaf(bq[d], We[j * 64 + d], acc);
        bqe[j] = acc;
    }
}

// ---------- K1: per-node linear: q,k,v,skip,qe from relu(h_in) ----------
__global__ __launch_bounds__(256) void node_linear(
    const float* __restrict__ hin,
    const float* __restrict__ Wq, const float* __restrict__ Wk,
    const float* __restrict__ Wv, const float* __restrict__ Wsk,
    const float* __restrict__ Wqe,
    const float* __restrict__ bq, const float* __restrict__ bk,
    const float* __restrict__ bv, const float* __restrict__ bs,
    const float* __restrict__ bqe,
    float* __restrict__ q, float* __restrict__ k, float* __restrict__ v,
    float* __restrict__ skip, float* __restrict__ qe) {
    __shared__ float r[4][64];
    int wid = threadIdx.x >> 6, lane = threadIdx.x & 63;
    int n = blockIdx.x * 4 + wid;          // N % 4 == 0, always valid
    float xv = hin[n * 64 + lane];
    r[wid][lane] = xv > 0.f ? xv : 0.f;
    __syncthreads();
    float aq = 0.f, ak = 0.f, av = 0.f, as_ = 0.f, aqe = 0.f;
    #pragma unroll 8
    for (int j = 0; j < 64; ++j) {
        float rj = r[wid][j];
        aq  = fmaf(rj, Wq [j * 64 + lane], aq);
        ak  = fmaf(rj, Wk [j * 64 + lane], ak);
        av  = fmaf(rj, Wv [j * 64 + lane], av);
        as_ = fmaf(rj, Wsk[j * 64 + lane], as_);
        aqe = fmaf(rj, Wqe[j * 64 + lane], aqe);
    }
    int o = n * 64 + lane;
    q[o]    = aq  + bq[lane];
    k[o]    = ak  + bk[lane];
    v[o]    = av  + bv[lane];
    skip[o] = as_ + bs[lane];
    qe[o]   = aqe + bqe[lane];
}

// ---------- K2: per-edge logits + segment max ----------
__global__ __launch_bounds__(256) void edge_logits(
    const int* __restrict__ ei, const float* __restrict__ ea,
    const float* __restrict__ q, const float* __restrict__ k,
    const float* __restrict__ qe,
    float* __restrict__ logits, unsigned* __restrict__ mbuf) {
    int wid = threadIdx.x >> 6, lane = threadIdx.x & 63;
    int i = blockIdx.x * 4 + wid;          // E % 4 == 0
    int s = ei[i], d = ei[EE + i];
    size_t eo = (size_t)i * 64 + lane;
    float p = q[d * 64 + lane] * k[s * 64 + lane] +
              qe[d * 64 + lane] * ea[eo];
    #pragma unroll
    for (int off = 32; off; off >>= 1) p += __shfl_xor(p, off);
    if (lane == 0) {
        float lg = p * 0.125f;             // / sqrt(64)
        logits[i] = lg;
        atomicMax(&mbuf[d], fmap(lg));
    }
}

// ---------- K3: per-edge exp + scatter-add (unnormalized) ----------
__global__ __launch_bounds__(256) void edge_scatter(
    const int* __restrict__ ei, const float* __restrict__ ea,
    const float* __restrict__ v, const float* __restrict__ logits,
    const unsigned* __restrict__ mbuf,
    float* __restrict__ numv, float* __restrict__ accea,
    float* __restrict__ den) {
    int wid = threadIdx.x >> 6, lane = threadIdx.x & 63;
    int i = blockIdx.x * 4 + wid;
    int s = ei[i], d = ei[EE + i];
    float m = funmap(mbuf[d]);
    float a = expf(logits[i] - m);
    size_t eo = (size_t)i * 64 + lane;
    atomicAdd(&numv [d * 64 + lane], a * v[s * 64 + lane]);
    atomicAdd(&accea[d * 64 + lane], a * ea[eo]);
    if (lane == 0) atomicAdd(&den[d], a);
}

// ---------- K4: node epilogue: (numv + accea@We)/den + skip (+x) ----------
__global__ __launch_bounds__(256) void node_out(
    const float* __restrict__ numv, const float* __restrict__ accea,
    const float* __restrict__ den, const float* __restrict__ skip,
    const float* __restrict__ We, const float* __restrict__ addx,
    float* __restrict__ out) {
    __shared__ float ar[4][64];
    int wid = threadIdx.x >> 6, lane = threadIdx.x & 63;
    int n = blockIdx.x * 4 + wid;
    ar[wid][lane] = accea[n * 64 + lane];
    __syncthreads();
    float acc = 0.f;
    #pragma unroll 8
    for (int j = 0; j < 64; ++j) acc = fmaf(ar[wid][j], We[j * 64 + lane], acc);
    float dd = den[n];
    int o = n * 64 + lane;
    float val = (dd > 0.f) ? (numv[o] + acc) / dd : 0.f;
    val += skip[o];
    if (addx) val += addx[o];
    out[o] = val;
}

extern "C" void kernel_launch(void* const* d_in, const int* in_sizes, int n_in,
                              void* d_out, int out_size, void* d_ws, size_t ws_size,
                              hipStream_t stream) {
    const float* x  = (const float*)d_in[0];
    const int*   ei = (const int*)d_in[1];
    const float* ea = (const float*)d_in[2];
    const float* W[10];
    for (int i = 0; i < 10; ++i) W[i] = (const float*)d_in[3 + i];
    const float* B[8];
    for (int i = 0; i < 8; ++i) B[i] = (const float*)d_in[13 + i];

    const size_t ND = (size_t)NN * 64;   // 3,200,000
    float* ws = (float*)d_ws;
    float* q      = ws;                  // ND
    float* k      = ws + 1 * ND;         // ND
    float* v      = ws + 2 * ND;         // ND
    float* skip   = ws + 3 * ND;         // ND
    float* qe     = ws + 4 * ND;         // ND
    float* h      = ws + 5 * ND;         // ND (layer-1 output)
    float* logits = ws + 6 * ND;         // EE
    float* numv   = ws + 6 * ND + EE;    // ND   -- start of contiguous zero-init region
    float* accea  = numv + ND;           // ND
    float* den    = accea + ND;          // NN
    unsigned* m   = (unsigned*)(den + NN); // NN  -- end of zero-init region
    float* Wqe    = (float*)(m + NN);    // 4096
    float* bqe    = Wqe + 4096;          // 64

    const size_t zero_bytes = (2 * ND + 2 * (size_t)NN) * sizeof(float); // numv..m

    for (int l = 0; l < 2; ++l) {
        const float* Wq = W[l * 5 + 0], *Wk = W[l * 5 + 1], *Wv = W[l * 5 + 2];
        const float* We = W[l * 5 + 3], *Wsk = W[l * 5 + 4];
        const float* bq = B[l * 4 + 0], *bk = B[l * 4 + 1];
        const float* bv = B[l * 4 + 2], *bs = B[l * 4 + 3];

        (void)hipMemsetAsync(numv, 0, zero_bytes, stream);
        fuse_weights<<<65, 64, 0, stream>>>(Wq, We, bq, Wqe, bqe);
        node_linear<<<NN / 4, 256, 0, stream>>>(
            l ? h : x, Wq, Wk, Wv, Wsk, Wqe, bq, bk, bv, bs, bqe,
            q, k, v, skip, qe);
        edge_logits<<<EE / 4, 256, 0, stream>>>(ei, ea, q, k, qe, logits, m);
        edge_scatter<<<EE / 4, 256, 0, stream>>>(ei, ea, v, logits, m,
                                                 numv, accea, den);
        node_out<<<NN / 4, 256, 0, stream>>>(
            numv, accea, den, skip, We, l ? x : nullptr,
            l ? (float*)d_out : h);
    }
}

// Round 3
// 1012.722 us; speedup vs baseline: 1.7242x; 1.7242x over previous
//
#include <hip/hip_runtime.h>

#define NN 50000
#define EE 800000
#define SCAN_B 196   // ceil(50000/256)

// ---------- sort phase: CSR by dst ----------
__global__ __launch_bounds__(256) void k_hist(const int* __restrict__ ei,
                                              int* __restrict__ deg) {
    int i = blockIdx.x * 256 + threadIdx.x;
    if (i < EE) atomicAdd(&deg[ei[EE + i]], 1);
}

__global__ __launch_bounds__(256) void k_scanA(const int* __restrict__ deg,
                                               int* __restrict__ loc,
                                               int* __restrict__ bsum) {
    __shared__ int sh[256];
    int t = threadIdx.x, i = blockIdx.x * 256 + t;
    int v = (i < NN) ? deg[i] : 0;
    sh[t] = v;
    __syncthreads();
    for (int off = 1; off < 256; off <<= 1) {
        int u = (t >= off) ? sh[t - off] : 0;
        __syncthreads();
        sh[t] += u;
        __syncthreads();
    }
    if (i < NN) loc[i] = sh[t] - v;          // exclusive within block
    if (t == 255) bsum[blockIdx.x] = sh[255];
}

__global__ __launch_bounds__(256) void k_scanB(const int* __restrict__ bsum,
                                               int* __restrict__ boff) {
    __shared__ int sh[256];
    int t = threadIdx.x;
    int v = (t < SCAN_B) ? bsum[t] : 0;
    sh[t] = v;
    __syncthreads();
    for (int off = 1; off < 256; off <<= 1) {
        int u = (t >= off) ? sh[t - off] : 0;
        __syncthreads();
        sh[t] += u;
        __syncthreads();
    }
    if (t < SCAN_B) boff[t] = sh[t] - v;     // exclusive across blocks
}

__global__ __launch_bounds__(256) void k_scanC(const int* __restrict__ loc,
                                               const int* __restrict__ boff,
                                               int* __restrict__ rowptr,
                                               int* __restrict__ cursor) {
    int t = threadIdx.x, i = blockIdx.x * 256 + t;
    if (i < NN) {
        int r = loc[i] + boff[blockIdx.x];
        rowptr[i] = r;
        cursor[i] = r;
    }
    if (i == 0) rowptr[NN] = EE;
}

__global__ __launch_bounds__(256) void k_fill(const int* __restrict__ ei,
                                              int* __restrict__ cursor,
                                              int* __restrict__ esrc,
                                              int* __restrict__ eidx) {
    int i = blockIdx.x * 256 + threadIdx.x;
    if (i < EE) {
        int d = ei[EE + i];
        int pos = atomicAdd(&cursor[d], 1);
        esrc[pos] = ei[i];
        eidx[pos] = i;
    }
}

// ---------- K0: Wqe = Wq @ We^T, bqe = bq @ We^T ----------
__global__ __launch_bounds__(64) void fuse_weights(
    const float* __restrict__ Wq, const float* __restrict__ We,
    const float* __restrict__ bq, float* __restrict__ Wqe,
    float* __restrict__ bqe) {
    int j = threadIdx.x;
    int t = blockIdx.x;
    if (t < 64) {
        float acc = 0.f;
        #pragma unroll
        for (int d = 0; d < 64; ++d) acc = fmaf(Wq[t * 64 + d], We[j * 64 + d], acc);
        Wqe[t * 64 + j] = acc;
    } else {
        float acc = 0.f;
        #pragma unroll
        for (int d = 0; d < 64; ++d) acc = fmaf(bq[d], We[j * 64 + d], acc);
        bqe[j] = acc;
    }
}

// ---------- K1: per-node linear: q,k,v,skip,qe from relu(h_in) ----------
__global__ __launch_bounds__(256) void node_linear(
    const float* __restrict__ hin,
    const float* __restrict__ Wq, const float* __restrict__ Wk,
    const float* __restrict__ Wv, const float* __restrict__ Wsk,
    const float* __restrict__ Wqe,
    const float* __restrict__ bq, const float* __restrict__ bk,
    const float* __restrict__ bv, const float* __restrict__ bs,
    const float* __restrict__ bqe,
    float* __restrict__ q, float* __restrict__ k, float* __restrict__ v,
    float* __restrict__ skip, float* __restrict__ qe) {
    __shared__ float r[4][64];
    int wid = threadIdx.x >> 6, lane = threadIdx.x & 63;
    int n = blockIdx.x * 4 + wid;
    float xv = hin[n * 64 + lane];
    r[wid][lane] = xv > 0.f ? xv : 0.f;
    __syncthreads();
    float aq = 0.f, ak = 0.f, av = 0.f, as_ = 0.f, aqe = 0.f;
    #pragma unroll 8
    for (int j = 0; j < 64; ++j) {
        float rj = r[wid][j];
        aq  = fmaf(rj, Wq [j * 64 + lane], aq);
        ak  = fmaf(rj, Wk [j * 64 + lane], ak);
        av  = fmaf(rj, Wv [j * 64 + lane], av);
        as_ = fmaf(rj, Wsk[j * 64 + lane], as_);
        aqe = fmaf(rj, Wqe[j * 64 + lane], aqe);
    }
    int o = n * 64 + lane;
    q[o]    = aq  + bq[lane];
    k[o]    = ak  + bk[lane];
    v[o]    = av  + bv[lane];
    skip[o] = as_ + bs[lane];
    qe[o]   = aqe + bqe[lane];
}

// ---------- K2: fused per-node attention (one wave per dst node) ----------
__global__ __launch_bounds__(256) void node_attn(
    const int* __restrict__ rowptr, const int* __restrict__ esrc,
    const int* __restrict__ eidx,
    const float* __restrict__ ea, const float* __restrict__ q,
    const float* __restrict__ k, const float* __restrict__ v,
    const float* __restrict__ qe, const float* __restrict__ skip,
    const float* __restrict__ We, const float* __restrict__ addx,
    float* __restrict__ out) {
    __shared__ float sh[4][64];
    int wid = threadIdx.x >> 6, lane = threadIdx.x & 63;
    int n = blockIdx.x * 4 + wid;
    int beg = rowptr[n], end = rowptr[n + 1];
    size_t no = (size_t)n * 64 + lane;
    float qd = q[no], qed = qe[no];
    float m = -3.0e38f, den = 0.f, av = 0.f, ae = 0.f;

    float kv_n = 0.f, vv_n = 0.f, eav_n = 0.f;
    if (beg < end) {
        int s0 = esrc[beg], e0 = eidx[beg];
        kv_n  = k[(size_t)s0 * 64 + lane];
        vv_n  = v[(size_t)s0 * 64 + lane];
        eav_n = ea[(size_t)e0 * 64 + lane];
    }
    for (int p = beg; p < end; ++p) {
        float kv = kv_n, vv = vv_n, eav = eav_n;
        if (p + 1 < end) {
            int s2 = esrc[p + 1], e2 = eidx[p + 1];
            kv_n  = k[(size_t)s2 * 64 + lane];
            vv_n  = v[(size_t)s2 * 64 + lane];
            eav_n = ea[(size_t)e2 * 64 + lane];
        }
        float t = fmaf(qd, kv, qed * eav);
        #pragma unroll
        for (int off = 32; off; off >>= 1) t += __shfl_xor(t, off);
        float lg = t * 0.125f;                 // / sqrt(64)
        if (lg > m) {                          // wave-uniform branch
            float sc = __expf(m - lg);         // exp(-3e38-x) underflows to 0 on first edge
            den *= sc; av *= sc; ae *= sc; m = lg;
        }
        float a = __expf(lg - m);
        den += a;
        av = fmaf(a, vv, av);
        ae = fmaf(a, eav, ae);
    }
    sh[wid][lane] = ae;
    __syncthreads();
    float r = 0.f;
    #pragma unroll 8
    for (int j = 0; j < 64; ++j) r = fmaf(sh[wid][j], We[j * 64 + lane], r);
    float o = (den > 0.f) ? (av + r) / den : 0.f;
    o += skip[no];
    if (addx) o += addx[no];
    out[no] = o;
}

extern "C" void kernel_launch(void* const* d_in, const int* in_sizes, int n_in,
                              void* d_out, int out_size, void* d_ws, size_t ws_size,
                              hipStream_t stream) {
    const float* x  = (const float*)d_in[0];
    const int*   ei = (const int*)d_in[1];
    const float* ea = (const float*)d_in[2];
    const float* W[10];
    for (int i = 0; i < 10; ++i) W[i] = (const float*)d_in[3 + i];
    const float* B[8];
    for (int i = 0; i < 8; ++i) B[i] = (const float*)d_in[13 + i];

    const size_t ND = (size_t)NN * 64;
    float* ws   = (float*)d_ws;
    float* q    = ws;
    float* k    = ws + 1 * ND;
    float* v    = ws + 2 * ND;
    float* skip = ws + 3 * ND;
    float* qe   = ws + 4 * ND;
    float* h    = ws + 5 * ND;
    int* deg    = (int*)(ws + 6 * ND);   // NN
    int* loc    = deg + NN;              // NN
    int* bsum   = loc + NN;              // 256
    int* boff   = bsum + 256;            // 256
    int* rowptr = boff + 256;            // NN+1
    int* cursor = rowptr + NN + 1;       // NN
    int* esrc   = cursor + NN;           // EE
    int* eidx   = esrc + EE;             // EE
    float* Wqe  = (float*)(eidx + EE);   // 4096
    float* bqe  = Wqe + 4096;            // 64

    // ---- build CSR (inputs are restored before every call, so rebuild) ----
    (void)hipMemsetAsync(deg, 0, NN * sizeof(int), stream);
    k_hist <<<(EE + 255) / 256, 256, 0, stream>>>(ei, deg);
    k_scanA<<<SCAN_B, 256, 0, stream>>>(deg, loc, bsum);
    k_scanB<<<1, 256, 0, stream>>>(bsum, boff);
    k_scanC<<<SCAN_B, 256, 0, stream>>>(loc, boff, rowptr, cursor);
    k_fill <<<(EE + 255) / 256, 256, 0, stream>>>(ei, cursor, esrc, eidx);

    for (int l = 0; l < 2; ++l) {
        const float* Wq = W[l * 5 + 0], *Wk = W[l * 5 + 1], *Wv = W[l * 5 + 2];
        const float* We = W[l * 5 + 3], *Wsk = W[l * 5 + 4];
        const float* bq = B[l * 4 + 0], *bk = B[l * 4 + 1];
        const float* bv = B[l * 4 + 2], *bs = B[l * 4 + 3];

        fuse_weights<<<65, 64, 0, stream>>>(Wq, We, bq, Wqe, bqe);
        node_linear<<<NN / 4, 256, 0, stream>>>(
            l ? h : x, Wq, Wk, Wv, Wsk, Wqe, bq, bk, bv, bs, bqe,
            q, k, v, skip, qe);
        node_attn<<<NN / 4, 256, 0, stream>>>(
            rowptr, esrc, eidx, ea, q, k, v, qe, skip, We,
            l ? x : nullptr, l ? (float*)d_out : h);
    }
}

// Round 4
// 898.134 us; speedup vs baseline: 1.9442x; 1.1276x over previous
//
#include <hip/hip_runtime.h>
#include <math.h>

#define NN 50000
#define EE 800000
#define SCAN_B 196   // ceil(50000/256)

// ---------- sort phase: CSR by dst ----------
__global__ __launch_bounds__(256) void k_hist(const int* __restrict__ ei,
                                              int* __restrict__ deg) {
    int i = blockIdx.x * 256 + threadIdx.x;
    if (i < EE) atomicAdd(&deg[ei[EE + i]], 1);
}

__global__ __launch_bounds__(256) void k_scanA(const int* __restrict__ deg,
                                               int* __restrict__ loc,
                                               int* __restrict__ bsum) {
    __shared__ int sh[256];
    int t = threadIdx.x, i = blockIdx.x * 256 + t;
    int v = (i < NN) ? deg[i] : 0;
    sh[t] = v;
    __syncthreads();
    for (int off = 1; off < 256; off <<= 1) {
        int u = (t >= off) ? sh[t - off] : 0;
        __syncthreads();
        sh[t] += u;
        __syncthreads();
    }
    if (i < NN) loc[i] = sh[t] - v;
    if (t == 255) bsum[blockIdx.x] = sh[255];
}

__global__ __launch_bounds__(256) void k_scanB(const int* __restrict__ bsum,
                                               int* __restrict__ boff) {
    __shared__ int sh[256];
    int t = threadIdx.x;
    int v = (t < SCAN_B) ? bsum[t] : 0;
    sh[t] = v;
    __syncthreads();
    for (int off = 1; off < 256; off <<= 1) {
        int u = (t >= off) ? sh[t - off] : 0;
        __syncthreads();
        sh[t] += u;
        __syncthreads();
    }
    if (t < SCAN_B) boff[t] = sh[t] - v;
}

__global__ __launch_bounds__(256) void k_scanC(const int* __restrict__ loc,
                                               const int* __restrict__ boff,
                                               int* __restrict__ rowptr,
                                               int* __restrict__ cursor) {
    int t = threadIdx.x, i = blockIdx.x * 256 + t;
    if (i < NN) {
        int r = loc[i] + boff[blockIdx.x];
        rowptr[i] = r;
        cursor[i] = r;
    }
    if (i == 0) rowptr[NN] = EE;
}

__global__ __launch_bounds__(256) void k_fill(const int* __restrict__ ei,
                                              int* __restrict__ cursor,
                                              int2* __restrict__ es) {
    int i = blockIdx.x * 256 + threadIdx.x;
    if (i < EE) {
        int d = ei[EE + i];
        int pos = atomicAdd(&cursor[d], 1);
        es[pos] = make_int2(ei[i], i);   // (src, edge-id)
    }
}

// ---------- K0: Wqe = Wq @ We^T, bqe = bq @ We^T ----------
__global__ __launch_bounds__(64) void fuse_weights(
    const float* __restrict__ Wq, const float* __restrict__ We,
    const float* __restrict__ bq, float* __restrict__ Wqe,
    float* __restrict__ bqe) {
    int j = threadIdx.x;
    int t = blockIdx.x;
    if (t < 64) {
        float acc = 0.f;
        #pragma unroll
        for (int d = 0; d < 64; ++d) acc = fmaf(Wq[t * 64 + d], We[j * 64 + d], acc);
        Wqe[t * 64 + j] = acc;
    } else {
        float acc = 0.f;
        #pragma unroll
        for (int d = 0; d < 64; ++d) acc = fmaf(bq[d], We[j * 64 + d], acc);
        bqe[j] = acc;
    }
}

// ---------- K1: per-node linear: q,k,v,skip,qe from relu(h_in) ----------
__global__ __launch_bounds__(256) void node_linear(
    const float* __restrict__ hin,
    const float* __restrict__ Wq, const float* __restrict__ Wk,
    const float* __restrict__ Wv, const float* __restrict__ Wsk,
    const float* __restrict__ Wqe,
    const float* __restrict__ bq, const float* __restrict__ bk,
    const float* __restrict__ bv, const float* __restrict__ bs,
    const float* __restrict__ bqe,
    float* __restrict__ q, float* __restrict__ k, float* __restrict__ v,
    float* __restrict__ skip, float* __restrict__ qe) {
    __shared__ float r[4][64];
    int wid = threadIdx.x >> 6, lane = threadIdx.x & 63;
    int n = blockIdx.x * 4 + wid;
    float xv = hin[n * 64 + lane];
    r[wid][lane] = xv > 0.f ? xv : 0.f;
    __syncthreads();
    float aq = 0.f, ak = 0.f, av = 0.f, as_ = 0.f, aqe = 0.f;
    #pragma unroll 8
    for (int j = 0; j < 64; ++j) {
        float rj = r[wid][j];
        aq  = fmaf(rj, Wq [j * 64 + lane], aq);
        ak  = fmaf(rj, Wk [j * 64 + lane], ak);
        av  = fmaf(rj, Wv [j * 64 + lane], av);
        as_ = fmaf(rj, Wsk[j * 64 + lane], as_);
        aqe = fmaf(rj, Wqe[j * 64 + lane], aqe);
    }
    int o = n * 64 + lane;
    q[o]    = aq  + bq[lane];
    k[o]    = ak  + bk[lane];
    v[o]    = av  + bv[lane];
    skip[o] = as_ + bs[lane];
    qe[o]   = aqe + bqe[lane];
}

__device__ __forceinline__ float dot4(float4 a, float4 b) {
    return fmaf(a.x, b.x, fmaf(a.y, b.y, fmaf(a.z, b.z, a.w * b.w)));
}
__device__ __forceinline__ float4 f4scale(float4 a, float s) {
    return make_float4(a.x * s, a.y * s, a.z * s, a.w * s);
}
__device__ __forceinline__ float4 f4fma(float s, float4 a, float4 acc) {
    return make_float4(fmaf(s, a.x, acc.x), fmaf(s, a.y, acc.y),
                       fmaf(s, a.z, acc.z), fmaf(s, a.w, acc.w));
}
__device__ __forceinline__ float4 f4shflxor_add(float4 a, int mask) {
    a.x += __shfl_xor(a.x, mask);
    a.y += __shfl_xor(a.y, mask);
    a.z += __shfl_xor(a.z, mask);
    a.w += __shfl_xor(a.w, mask);
    return a;
}

// ---------- K2: fused per-node attention, 4 edges/iter (16 lanes each) ----------
__global__ __launch_bounds__(256) void node_attn(
    const int* __restrict__ rowptr, const int2* __restrict__ es,
    const float* __restrict__ ea, const float* __restrict__ q,
    const float* __restrict__ k, const float* __restrict__ v,
    const float* __restrict__ qe, const float* __restrict__ skip,
    const float* __restrict__ We, const float* __restrict__ addx,
    float* __restrict__ out) {
    __shared__ float shA[4][64];   // Σ a·v
    __shared__ float shE[4][64];   // Σ a·ea
    int wid = threadIdx.x >> 6, lane = threadIdx.x & 63;
    int g = lane >> 4, li = lane & 15;          // group (edge slot), lane-in-group
    int n = blockIdx.x * 4 + wid;
    int beg = rowptr[n], end = rowptr[n + 1];

    const float4* q4  = (const float4*)q;
    const float4* qe4 = (const float4*)qe;
    const float4* k4  = (const float4*)k;
    const float4* v4  = (const float4*)v;
    const float4* ea4 = (const float4*)ea;

    float4 qd  = q4 [(size_t)n * 16 + li];
    float4 qed = qe4[(size_t)n * 16 + li];

    float m = -3.0e38f, den = 0.f;
    float4 av = make_float4(0, 0, 0, 0), ae = make_float4(0, 0, 0, 0);

    if (beg < end) {
        // prefetch iteration 0
        bool vldc; float4 kvc, vvc, evc;
        {
            int idx = beg + g; vldc = idx < end; int ci = vldc ? idx : beg;
            int2 se = es[ci];
            kvc = k4[(size_t)se.x * 16 + li];
            vvc = v4[(size_t)se.x * 16 + li];
            evc = ea4[(size_t)se.y * 16 + li];
        }
        for (int p = beg; p < end; p += 4) {
            bool vldn = false; float4 kvn, vvn, evn;
            if (p + 4 < end) {
                int idx = p + 4 + g; vldn = idx < end; int ci = vldn ? idx : beg;
                int2 se = es[ci];
                kvn = k4[(size_t)se.x * 16 + li];
                vvn = v4[(size_t)se.x * 16 + li];
                evn = ea4[(size_t)se.y * 16 + li];
            }
            float t = dot4(qd, kvc) + dot4(qed, evc);
            t += __shfl_xor(t, 1);
            t += __shfl_xor(t, 2);
            t += __shfl_xor(t, 4);
            t += __shfl_xor(t, 8);
            float lg = vldc ? t * 0.125f : -INFINITY;   // / sqrt(64)
            float mx = fmaxf(lg, __shfl_xor(lg, 16));
            mx = fmaxf(mx, __shfl_xor(mx, 32));
            if (mx > m) {                                // wave-uniform
                float sc = __expf(m - mx);
                den *= sc; av = f4scale(av, sc); ae = f4scale(ae, sc);
                m = mx;
            }
            float a = __expf(lg - m);                    // 0 for invalid slots
            den += a;
            av = f4fma(a, vvc, av);
            ae = f4fma(a, evc, ae);
            vldc = vldn; kvc = kvn; vvc = vvn; evc = evn;
        }
    }
    // cross-group reductions (groups hold disjoint edge subsets, same dims)
    av = f4shflxor_add(av, 16); av = f4shflxor_add(av, 32);
    ae = f4shflxor_add(ae, 16); ae = f4shflxor_add(ae, 32);
    den += __shfl_xor(den, 16); den += __shfl_xor(den, 32);
    if (lane < 16) {
        *(float4*)&shA[wid][lane * 4] = av;
        *(float4*)&shE[wid][lane * 4] = ae;
    }
    __syncthreads();
    float r = 0.f;
    #pragma unroll 8
    for (int j = 0; j < 64; ++j) r = fmaf(shE[wid][j], We[j * 64 + lane], r);
    size_t no = (size_t)n * 64 + lane;
    float o = (den > 0.f) ? (shA[wid][lane] + r) / den : 0.f;
    o += skip[no];
    if (addx) o += addx[no];
    out[no] = o;
}

extern "C" void kernel_launch(void* const* d_in, const int* in_sizes, int n_in,
                              void* d_out, int out_size, void* d_ws, size_t ws_size,
                              hipStream_t stream) {
    const float* x  = (const float*)d_in[0];
    const int*   ei = (const int*)d_in[1];
    const float* ea = (const float*)d_in[2];
    const float* W[10];
    for (int i = 0; i < 10; ++i) W[i] = (const float*)d_in[3 + i];
    const float* B[8];
    for (int i = 0; i < 8; ++i) B[i] = (const float*)d_in[13 + i];

    const size_t ND = (size_t)NN * 64;
    float* ws   = (float*)d_ws;
    float* q    = ws;
    float* k    = ws + 1 * ND;
    float* v    = ws + 2 * ND;
    float* skip = ws + 3 * ND;
    float* qe   = ws + 4 * ND;
    float* h    = ws + 5 * ND;
    int* deg    = (int*)(ws + 6 * ND);   // NN
    int* loc    = deg + NN;              // NN
    int* bsum   = loc + NN;              // 256
    int* boff   = bsum + 256;            // 256
    int* rowptr = boff + 256;            // NN+1
    int* cursor = rowptr + NN + 1;       // NN (+1 pad to keep es 8B-aligned)
    int2* es    = (int2*)(cursor + NN + 1); // EE int2
    float* Wqe  = (float*)(es + EE);     // 4096
    float* bqe  = Wqe + 4096;            // 64

    // ---- build CSR (inputs re-poisoned every call, so rebuild) ----
    (void)hipMemsetAsync(deg, 0, NN * sizeof(int), stream);
    k_hist <<<(EE + 255) / 256, 256, 0, stream>>>(ei, deg);
    k_scanA<<<SCAN_B, 256, 0, stream>>>(deg, loc, bsum);
    k_scanB<<<1, 256, 0, stream>>>(bsum, boff);
    k_scanC<<<SCAN_B, 256, 0, stream>>>(loc, boff, rowptr, cursor);
    k_fill <<<(EE + 255) / 256, 256, 0, stream>>>(ei, cursor, es);

    for (int l = 0; l < 2; ++l) {
        const float* Wq = W[l * 5 + 0], *Wk = W[l * 5 + 1], *Wv = W[l * 5 + 2];
        const float* We = W[l * 5 + 3], *Wsk = W[l * 5 + 4];
        const float* bq = B[l * 4 + 0], *bk = B[l * 4 + 1];
        const float* bv = B[l * 4 + 2], *bs = B[l * 4 + 3];

        fuse_weights<<<65, 64, 0, stream>>>(Wq, We, bq, Wqe, bqe);
        node_linear<<<NN / 4, 256, 0, stream>>>(
            l ? h : x, Wq, Wk, Wv, Wsk, Wqe, bq, bk, bv, bs, bqe,
            q, k, v, skip, qe);
        node_attn<<<NN / 4, 256, 0, stream>>>(
            rowptr, es, ea, q, k, v, qe, skip, We,
            l ? x : nullptr, l ? (float*)d_out : h);
    }
}